// Round 7
// baseline (102.080 us; speedup 1.0000x reference)
//
#include <hip/hip_runtime.h>
#include <math.h>

#define NSTEP 69
#define OBS 8

namespace {

constexpr float kDT = 60.0f / 69.0f;

constexpr float interp_e(float t) {
    constexpr float DTm[16] = {0.f,2.f,4.f,6.f,8.f,10.f,12.f,14.f,16.f,18.f,20.f,25.f,30.f,40.f,50.f,60.f};
    constexpr float EP[16]  = {0.01713f,0.145f,0.2442f,0.7659f,1.0f,0.8605f,0.7829f,0.5705f,
                               0.6217f,0.331f,0.3388f,0.3116f,0.05062f,0.02504f,0.01163f,0.01163f};
    if (t >= 60.0f) return EP[15];
    if (t <= 0.0f)  return EP[0];
    int k = 0;
    for (int m = 0; m < 15; m++) if (t >= DTm[m]) k = m;
    float u = (t - DTm[k]) / (DTm[k + 1] - DTm[k]);
    return EP[k] + u * (EP[k + 1] - EP[k]);
}

// {lo, mid, hi, pad} per step, padded so the distance-1 prefetch stays in bounds.
struct EQuad { float lo, mid, hi, pad; };
struct ETab4 { EQuad q[NSTEP + 1]; };

constexpr ETab4 make_etab4() {
    ETab4 e{};
    for (int s = 0; s < NSTEP; s++) {
        float t0 = (float)s * kDT;
        e.q[s].lo  = interp_e(t0);
        e.q[s].mid = interp_e(t0 + 0.5f * kDT);
        e.q[s].hi  = interp_e(t0 + kDT);
        e.q[s].pad = 0.0f;
    }
    e.q[NSTEP] = e.q[NSTEP - 1];
    return e;
}

} // namespace

__constant__ ETab4 ETAB4 = make_etab4();

// DPP quad_perm helper (VALU cross-lane within each 4-lane quad, no LDS).
// ctrl bits [1:0]=lane0 src, [3:2]=lane1, [5:4]=lane2, [7:6]=lane3.
template <int CTRL>
__device__ __forceinline__ float qperm(float x) {
    return __int_as_float(
        __builtin_amdgcn_mov_dpp(__float_as_int(x), CTRL, 0xf, 0xf, true));
}
#define QP_SHIFT 0x90  // [0,0,1,2]: lane p <- lane p-1 (lane0 gets own; overridden)
#define QP_BC3   0xFF  // [3,3,3,3]: all lanes <- lane3

// 4-lanes-per-system decomposition.
//
// R0-R6 evidence: per-wave progress is rate-limited (~6.5-9 cyc/instr at
// 1 wave/SIMD) independent of code shape, ILP, registers, i-fetch, and even
// instruction count; but co-resident waves overlap almost perfectly under
// the limiter (R2: a full duplicate wave cost only +14% wall). So the only
// winning move is less work per wave + more waves: split each ODE system
// across a DPP quad.
//
//   lane p in [0,4) owns chain slots {2p, 2p+1} of the 8-slot w-chain
//     (w_i = r*q_i; slots: w_q1..w_q7, w_out), held as scalars sL,sH.
//   prev(sL of lane p) = sH of lane p-1  -> quad_perm[0,0,1,2]
//     (lane0's prev = r*x2, selected by cndmask)
//   w_out (for dx1 feedback) = sH of lane3 -> quad_perm[3,3,3,3]
//   specials x0,x1,x2 + RK4 capture state replicated in all 4 lanes.
//
// Geometry: B*4 threads = 4096 waves = 4 waves/SIMD; per-wave stream
// ~90 instr/iter (~0.4x of the packed 1-lane version).
__global__ __launch_bounds__(256, 4) void stats5_kernel(
    const float* __restrict__ params,
    const float* __restrict__ design,
    const float* __restrict__ noise,
    float* __restrict__ out,
    int B)
{
    int tid = blockIdx.x * blockDim.x + threadIdx.x;
    int b   = tid >> 2;                 // system id (uniform within quad)
    int p   = threadIdx.x & 3;          // quad lane (matches DPP quads)
    if (b >= B) return;
    const bool isL0 = (p == 0);

    // ---- design readout (wave-uniform -> SGPR)
    int ij[OBS], ij1[OBS]; float wj[OBS], w1j[OBS];
    #pragma unroll
    for (int j = 0; j < OBS; j++) {
        float pos = design[j] * (1.0f / kDT);
        int i = (int)pos;
        i = i < 0 ? 0 : (i > NSTEP - 1 ? NSTEP - 1 : i);
        float w = pos - (float)i;
        ij[j]  = __builtin_amdgcn_readfirstlane(i);
        ij1[j] = ij[j] + 1;
        int wb = __builtin_amdgcn_readfirstlane(__float_as_int(w));
        wj[j]  = __int_as_float(wb);
        w1j[j] = 1.0f - wj[j];
    }

    unsigned long long m_lo = 0ull, m_hi = 0ull;
    #pragma unroll
    for (int j = 0; j < OBS; j++) {
        if (ij[j]  < 64) m_lo |= 1ull << ij[j];  else m_hi |= 1ull << (ij[j]  - 64);
        if (ij1[j] < 64) m_lo |= 1ull << ij1[j]; else m_hi |= 1ull << (ij1[j] - 64);
    }

    // ---- parameter transform (replicated in all 4 lanes of the quad)
    float p0 = params[3 * b], p1 = params[3 * b + 1], p2 = params[3 * b + 2];
    const float INV_SQRT2 = 0.7071067811865476f;
    float k1  = fmaf(0.5f * erfcf(-p0 * INV_SQRT2), 2.5f,  0.5f);
    float k2  = fmaf(0.5f * erfcf(-p1 * INV_SQRT2), 0.15f, 0.05f);
    float tau = fmaf(0.5f * erfcf(-p2 * INV_SQRT2), 6.0f,  4.0f);
    float r   = 8.0f / tau;

    const float hdt = 0.5f * kDT;
    const float c6  = kDT * (1.0f / 6.0f);
    const float k2r = 0.125f * k2 * tau;   // k2 / r (no division)
    const float crh = hdt * r;             // half-step chain scale
    const float crf = kDT * r;             // full-step chain scale
    const float c6r = c6 * r;              // final chain scale

    // ---- hoist epilogue load: lane p takes float4 #p of this system's noise
    long long base = (long long)b * 16;
    long long nb   = (long long)B * 16;
    float4 nmy = ((const float4*)(noise + base))[p];

    float a12[OBS], a0[OBS], b12[OBS], b0[OBS];
    #pragma unroll
    for (int j = 0; j < OBS; j++) { a12[j] = 0.f; a0[j] = 0.f; b12[j] = 0.f; b0[j] = 0.f; }

    float x0 = 3.71f, x1 = 0.f, x2 = 0.f;
    float WL = 0.f, WH = 0.f;              // this lane's two chain slots

    if (m_lo & 1ull) {
        #pragma unroll
        for (int j = 0; j < OBS; j++)
            if (ij[j] == 0) { a12[j] = 0.f; a0[j] = 3.71f; }
    }

    // DERIV at (X0,X1,X2, VL,VH): specials derivs + this lane's chain diffs.
    auto DERIV = [&](float k1E, float X0, float X1, float X2, float VL, float VH,
                     float& D0, float& D1, float& D2, float& GL, float& GH) {
        float vprev = qperm<QP_SHIFT>(VH);       // lane p <- lane p-1's VH
        float wout  = qperm<QP_BC3>(VH);         // lane3's VH to all
        float prev  = isL0 ? (r * X2) : vprev;   // slot0's prev = r*x3
        float a  = k1E * X0;
        float sq = X1 * X1;
        D0 = fmaf(k2r, wout, -a);
        D1 = a - sq;
        D2 = fmaf(-k2, X2, sq);
        GL = prev - VL;
        GH = VL - VH;
    };

    // ---- rolled time loop, E prefetched one step ahead
    const float4* et = reinterpret_cast<const float4*>(&ETAB4.q[0].lo);
    float4 eC = et[0];

    #pragma unroll 1
    for (int s = 0; s < NSTEP; s++) {
        float4 eN = et[s + 1];
        const float ea = eC.x, eb = eC.y, ec = eC.z;
        float k1a = k1 * ea, k1b = k1 * eb, k1c = k1 * ec;

        float d10, d11, d12, G1L, G1H;
        DERIV(k1a, x0, x1, x2, WL, WH, d10, d11, d12, G1L, G1H);
        float t0 = fmaf(hdt, d10, x0);
        float t1 = fmaf(hdt, d11, x1);
        float t2 = fmaf(hdt, d12, x2);
        float UL = fmaf(crh, G1L, WL);
        float UH = fmaf(crh, G1H, WH);

        float d20, d21, d22, G2L, G2H;
        DERIV(k1b, t0, t1, t2, UL, UH, d20, d21, d22, G2L, G2H);
        float ax0 = fmaf(2.0f, d20, d10);
        float ax1 = fmaf(2.0f, d21, d11);
        float ax2 = fmaf(2.0f, d22, d12);
        float AL  = fmaf(2.0f, G2L, G1L);
        float AH  = fmaf(2.0f, G2H, G1H);
        t0 = fmaf(hdt, d20, x0);
        t1 = fmaf(hdt, d21, x1);
        t2 = fmaf(hdt, d22, x2);
        UL = fmaf(crh, G2L, WL);
        UH = fmaf(crh, G2H, WH);

        float d30, d31, d32, G3L, G3H;
        DERIV(k1b, t0, t1, t2, UL, UH, d30, d31, d32, G3L, G3H);
        ax0 = fmaf(2.0f, d30, ax0);
        ax1 = fmaf(2.0f, d31, ax1);
        ax2 = fmaf(2.0f, d32, ax2);
        AL  = fmaf(2.0f, G3L, AL);
        AH  = fmaf(2.0f, G3H, AH);
        t0 = fmaf(kDT, d30, x0);
        t1 = fmaf(kDT, d31, x1);
        t2 = fmaf(kDT, d32, x2);
        UL = fmaf(crf, G3L, WL);
        UH = fmaf(crf, G3H, WH);

        float d40, d41, d42, G4L, G4H;
        DERIV(k1c, t0, t1, t2, UL, UH, d40, d41, d42, G4L, G4H);
        ax0 += d40; ax1 += d41; ax2 += d42;
        x0 = fmaf(c6, ax0, x0);
        x1 = fmaf(c6, ax1, x1);
        x2 = fmaf(c6, ax2, x2);
        AL += G4L; AH += G4H;
        WL = fmaf(c6r, AL, WL);
        WH = fmaf(c6r, AH, WH);

        // uniform observation-mask test: a few SALU + s_cbranch, taken <=16/69
        const int ti = s + 1;
        unsigned long long mm = (ti < 64) ? (m_lo >> ti) : (m_hi >> (ti - 64));
        if (__builtin_expect((int)(mm & 1ull), 0)) {
            float s12 = x1 + x2;
            #pragma unroll
            for (int j = 0; j < OBS; j++) {
                if (ti == ij[j])  { a12[j] = s12; a0[j] = x0; }
                if (ti == ij1[j]) { b12[j] = s12; b0[j] = x0; }
            }
        }
        eC = eN;
    }

    // ---- epilogue: all capture state is lane-redundant; lane p emits
    // float4 #p of the 16-float output row (coalesced 64B per quad).
    float o1[OBS], o2[OBS];
    #pragma unroll
    for (int j = 0; j < OBS; j++) {
        o1[j] = 0.33f * fmaf(w1j[j], a12[j], wj[j] * b12[j]);
        o2[j] = 0.26f * fmaf(w1j[j], a0[j] + a12[j], wj[j] * (b0[j] + b12[j]));
    }

    float4 v0 = make_float4(o1[0], o1[1], o1[2], o1[3]);
    float4 v1 = make_float4(o1[4], o1[5], o1[6], o1[7]);
    float4 v2 = make_float4(o2[0], o2[1], o2[2], o2[3]);
    float4 v3 = make_float4(o2[4], o2[5], o2[6], o2[7]);

    float4 mine = (p == 0) ? v0 : (p == 1) ? v1 : (p == 2) ? v2 : v3;

    ((float4*)(out + base))[p] = mine;
    ((float4*)(out + nb + base))[p] =
        make_float4(fmaf(0.01f, nmy.x, mine.x), fmaf(0.01f, nmy.y, mine.y),
                    fmaf(0.01f, nmy.z, mine.z), fmaf(0.01f, nmy.w, mine.w));
}

extern "C" void kernel_launch(void* const* d_in, const int* in_sizes, int n_in,
                              void* d_out, int out_size, void* d_ws, size_t ws_size,
                              hipStream_t stream) {
    const float* params = (const float*)d_in[0];
    const float* design = (const float*)d_in[1];
    const float* noise  = (const float*)d_in[2];
    float* out = (float*)d_out;
    int B = in_sizes[0] / 3;
    int block = 256;
    // 4 lanes per system -> B*4 threads
    long long threads = (long long)B * 4;
    int grid = (int)((threads + block - 1) / block);
    stats5_kernel<<<grid, block, 0, stream>>>(params, design, noise, out, B);
}

// Round 8
// 88.076 us; speedup vs baseline: 1.1590x; 1.1590x over previous
//
#include <hip/hip_runtime.h>
#include <math.h>

#define NSTEP 69
#define OBS 8

namespace {

constexpr float kDT = 60.0f / 69.0f;

constexpr float interp_e(float t) {
    constexpr float DTm[16] = {0.f,2.f,4.f,6.f,8.f,10.f,12.f,14.f,16.f,18.f,20.f,25.f,30.f,40.f,50.f,60.f};
    constexpr float EP[16]  = {0.01713f,0.145f,0.2442f,0.7659f,1.0f,0.8605f,0.7829f,0.5705f,
                               0.6217f,0.331f,0.3388f,0.3116f,0.05062f,0.02504f,0.01163f,0.01163f};
    if (t >= 60.0f) return EP[15];
    if (t <= 0.0f)  return EP[0];
    int k = 0;
    for (int m = 0; m < 15; m++) if (t >= DTm[m]) k = m;
    float u = (t - DTm[k]) / (DTm[k + 1] - DTm[k]);
    return EP[k] + u * (EP[k + 1] - EP[k]);
}

// {lo, mid, hi, pad} per step, padded so the distance-1 prefetch stays in bounds.
struct EQuad { float lo, mid, hi, pad; };
struct ETab4 { EQuad q[NSTEP + 1]; };

constexpr ETab4 make_etab4() {
    ETab4 e{};
    for (int s = 0; s < NSTEP; s++) {
        float t0 = (float)s * kDT;
        e.q[s].lo  = interp_e(t0);
        e.q[s].mid = interp_e(t0 + 0.5f * kDT);
        e.q[s].hi  = interp_e(t0 + kDT);
        e.q[s].pad = 0.0f;
    }
    e.q[NSTEP] = e.q[NSTEP - 1];
    return e;
}

} // namespace

__constant__ ETab4 ETAB4 = make_etab4();

// DPP quad_perm helper (VALU cross-lane within each 4-lane quad, no LDS).
// ctrl bits [1:0]=lane0 src, [3:2]=lane1, [5:4]=lane2, [7:6]=lane3.
template <int CTRL>
__device__ __forceinline__ float qperm(float x) {
    return __int_as_float(
        __builtin_amdgcn_mov_dpp(__float_as_int(x), CTRL, 0xf, 0xf, true));
}
// Pairs within each quad: system A = lanes {0,1}, system B = lanes {2,3}.
#define QP_PREV 0xA0  // [0,0,2,2]: odd lane <- even partner (even lanes: own, unused)
#define QP_OUT  0xF5  // [1,1,3,3]: both lanes <- odd partner (w_out broadcast)

// 2-lanes-per-system decomposition.
//
// Measured issue model (R1/R2/R7): each wave is capped at ~1 VALU instr per
// 6.5 cyc; aggregate rate saturates with wave count (1w: 0.154, 2w: 0.27,
// 4w: 0.355 instr/cyc per SIMD). Wall = per-SIMD instructions / rate(n).
// R7's 4-lane split paid 3x instructions for rate 0.355 -> lost. This 2-lane
// split keeps per-SIMD instructions at ~R1 level (~14.6k vs 15.2k) while
// doubling the rate to 0.27: predicted ~54k cyc vs R1's 99k.
//
//   lane p in {0,1} owns chain slots [4p, 4p+3] of the 8-slot w-chain
//     (w_i = r*q_i; slots: w_q1..w_q7, w_out), held as W0..W3 scalars.
//   prev(slot0 of lane1) = W3 of lane0 -> quad_perm[0,0,2,2]
//   prev(slot0 of lane0) = r*x2        -> cndmask on lane parity
//   w_out (dx1 feedback) = W3 of lane1 -> quad_perm[1,1,3,3]
//   specials x0,x1,x2 + RK4 capture state replicated in both lanes.
//
// Geometry: B*2 threads = 2048 waves = 2 waves/SIMD.
__global__ __launch_bounds__(256, 2) void stats5_kernel(
    const float* __restrict__ params,
    const float* __restrict__ design,
    const float* __restrict__ noise,
    float* __restrict__ out,
    int B)
{
    int tid = blockIdx.x * blockDim.x + threadIdx.x;
    int b   = tid >> 1;                 // system id (uniform within pair)
    int p   = threadIdx.x & 1;          // pair lane (aligned with DPP quads)
    if (b >= B) return;
    const bool isOdd = (p != 0);

    // ---- design readout (wave-uniform -> SGPR)
    int ij[OBS], ij1[OBS]; float wj[OBS], w1j[OBS];
    #pragma unroll
    for (int j = 0; j < OBS; j++) {
        float pos = design[j] * (1.0f / kDT);
        int i = (int)pos;
        i = i < 0 ? 0 : (i > NSTEP - 1 ? NSTEP - 1 : i);
        float w = pos - (float)i;
        ij[j]  = __builtin_amdgcn_readfirstlane(i);
        ij1[j] = ij[j] + 1;
        int wb = __builtin_amdgcn_readfirstlane(__float_as_int(w));
        wj[j]  = __int_as_float(wb);
        w1j[j] = 1.0f - wj[j];
    }

    unsigned long long m_lo = 0ull, m_hi = 0ull;
    #pragma unroll
    for (int j = 0; j < OBS; j++) {
        if (ij[j]  < 64) m_lo |= 1ull << ij[j];  else m_hi |= 1ull << (ij[j]  - 64);
        if (ij1[j] < 64) m_lo |= 1ull << ij1[j]; else m_hi |= 1ull << (ij1[j] - 64);
    }

    // ---- parameter transform (replicated in both lanes of the pair)
    float p0 = params[3 * b], p1 = params[3 * b + 1], p2 = params[3 * b + 2];
    const float INV_SQRT2 = 0.7071067811865476f;
    float k1  = fmaf(0.5f * erfcf(-p0 * INV_SQRT2), 2.5f,  0.5f);
    float k2  = fmaf(0.5f * erfcf(-p1 * INV_SQRT2), 0.15f, 0.05f);
    float tau = fmaf(0.5f * erfcf(-p2 * INV_SQRT2), 6.0f,  4.0f);
    float r   = 8.0f / tau;

    const float hdt = 0.5f * kDT;
    const float c6  = kDT * (1.0f / 6.0f);
    const float k2r = 0.125f * k2 * tau;   // k2 / r (no division)
    const float crh = hdt * r;             // half-step chain scale
    const float crf = kDT * r;             // full-step chain scale
    const float c6r = c6 * r;              // final chain scale

    // ---- hoist epilogue loads: lane p takes float4 #2p and #2p+1
    long long base = (long long)b * 16;
    long long nb   = (long long)B * 16;
    const float4* nz = (const float4*)(noise + base);
    float4 nA = nz[2 * p], nB = nz[2 * p + 1];

    float a12[OBS], a0[OBS], b12[OBS], b0[OBS];
    #pragma unroll
    for (int j = 0; j < OBS; j++) { a12[j] = 0.f; a0[j] = 0.f; b12[j] = 0.f; b0[j] = 0.f; }

    float x0 = 3.71f, x1 = 0.f, x2 = 0.f;
    float W0 = 0.f, W1 = 0.f, W2 = 0.f, W3 = 0.f;   // this lane's 4 chain slots

    if (m_lo & 1ull) {
        #pragma unroll
        for (int j = 0; j < OBS; j++)
            if (ij[j] == 0) { a12[j] = 0.f; a0[j] = 3.71f; }
    }

    // DERIV: specials derivs + this lane's 4 chain diffs.
    auto DERIV = [&](float k1E, float X0, float X1, float X2,
                     float V0, float V1, float V2, float V3,
                     float& D0, float& D1, float& D2,
                     float& G0, float& G1, float& G2, float& G3) {
        float vprev = qperm<QP_PREV>(V3);        // odd lane <- even lane's V3
        float wout  = qperm<QP_OUT>(V3);         // both lanes <- odd lane's V3
        float prev  = isOdd ? vprev : (r * X2);  // even lane slot0: prev = r*x3
        float a  = k1E * X0;
        float sq = X1 * X1;
        D0 = fmaf(k2r, wout, -a);
        D1 = a - sq;
        D2 = fmaf(-k2, X2, sq);
        G0 = prev - V0;
        G1 = V0 - V1;
        G2 = V1 - V2;
        G3 = V2 - V3;
    };

    // ---- rolled time loop, E prefetched one step ahead
    const float4* et = reinterpret_cast<const float4*>(&ETAB4.q[0].lo);
    float4 eC = et[0];

    #pragma unroll 1
    for (int s = 0; s < NSTEP; s++) {
        float4 eN = et[s + 1];
        const float ea = eC.x, eb = eC.y, ec = eC.z;
        float k1a = k1 * ea, k1b = k1 * eb, k1c = k1 * ec;

        float d10, d11, d12, G10, G11, G12, G13;
        DERIV(k1a, x0, x1, x2, W0, W1, W2, W3, d10, d11, d12, G10, G11, G12, G13);
        float t0 = fmaf(hdt, d10, x0);
        float t1 = fmaf(hdt, d11, x1);
        float t2 = fmaf(hdt, d12, x2);
        float U0 = fmaf(crh, G10, W0);
        float U1 = fmaf(crh, G11, W1);
        float U2 = fmaf(crh, G12, W2);
        float U3 = fmaf(crh, G13, W3);

        float d20, d21, d22, G20, G21, G22, G23;
        DERIV(k1b, t0, t1, t2, U0, U1, U2, U3, d20, d21, d22, G20, G21, G22, G23);
        float ax0 = fmaf(2.0f, d20, d10);
        float ax1 = fmaf(2.0f, d21, d11);
        float ax2 = fmaf(2.0f, d22, d12);
        float A0  = fmaf(2.0f, G20, G10);
        float A1  = fmaf(2.0f, G21, G11);
        float A2  = fmaf(2.0f, G22, G12);
        float A3  = fmaf(2.0f, G23, G13);
        t0 = fmaf(hdt, d20, x0);
        t1 = fmaf(hdt, d21, x1);
        t2 = fmaf(hdt, d22, x2);
        U0 = fmaf(crh, G20, W0);
        U1 = fmaf(crh, G21, W1);
        U2 = fmaf(crh, G22, W2);
        U3 = fmaf(crh, G23, W3);

        float d30, d31, d32, G30, G31, G32, G33;
        DERIV(k1b, t0, t1, t2, U0, U1, U2, U3, d30, d31, d32, G30, G31, G32, G33);
        ax0 = fmaf(2.0f, d30, ax0);
        ax1 = fmaf(2.0f, d31, ax1);
        ax2 = fmaf(2.0f, d32, ax2);
        A0  = fmaf(2.0f, G30, A0);
        A1  = fmaf(2.0f, G31, A1);
        A2  = fmaf(2.0f, G32, A2);
        A3  = fmaf(2.0f, G33, A3);
        t0 = fmaf(kDT, d30, x0);
        t1 = fmaf(kDT, d31, x1);
        t2 = fmaf(kDT, d32, x2);
        U0 = fmaf(crf, G30, W0);
        U1 = fmaf(crf, G31, W1);
        U2 = fmaf(crf, G32, W2);
        U3 = fmaf(crf, G33, W3);

        float d40, d41, d42, G40, G41, G42, G43;
        DERIV(k1c, t0, t1, t2, U0, U1, U2, U3, d40, d41, d42, G40, G41, G42, G43);
        ax0 += d40; ax1 += d41; ax2 += d42;
        x0 = fmaf(c6, ax0, x0);
        x1 = fmaf(c6, ax1, x1);
        x2 = fmaf(c6, ax2, x2);
        A0 += G40; A1 += G41; A2 += G42; A3 += G43;
        W0 = fmaf(c6r, A0, W0);
        W1 = fmaf(c6r, A1, W1);
        W2 = fmaf(c6r, A2, W2);
        W3 = fmaf(c6r, A3, W3);

        // uniform observation-mask test: a few SALU + s_cbranch, taken <=16/69
        const int ti = s + 1;
        unsigned long long mm = (ti < 64) ? (m_lo >> ti) : (m_hi >> (ti - 64));
        if (__builtin_expect((int)(mm & 1ull), 0)) {
            float s12 = x1 + x2;
            #pragma unroll
            for (int j = 0; j < OBS; j++) {
                if (ti == ij[j])  { a12[j] = s12; a0[j] = x0; }
                if (ti == ij1[j]) { b12[j] = s12; b0[j] = x0; }
            }
        }
        eC = eN;
    }

    // ---- epilogue: capture state is lane-redundant; lane p emits
    // float4 #2p and #2p+1 of the 16-float output row (coalesced per pair).
    float o1[OBS], o2[OBS];
    #pragma unroll
    for (int j = 0; j < OBS; j++) {
        o1[j] = 0.33f * fmaf(w1j[j], a12[j], wj[j] * b12[j]);
        o2[j] = 0.26f * fmaf(w1j[j], a0[j] + a12[j], wj[j] * (b0[j] + b12[j]));
    }

    float4 v0 = make_float4(o1[0], o1[1], o1[2], o1[3]);
    float4 v1 = make_float4(o1[4], o1[5], o1[6], o1[7]);
    float4 v2 = make_float4(o2[0], o2[1], o2[2], o2[3]);
    float4 v3 = make_float4(o2[4], o2[5], o2[6], o2[7]);

    float4 mA = p ? v2 : v0;
    float4 mB = p ? v3 : v1;

    float4* outv = (float4*)(out + base);
    float4* outn = (float4*)(out + nb + base);
    outv[2 * p]     = mA;
    outv[2 * p + 1] = mB;
    outn[2 * p]     = make_float4(fmaf(0.01f, nA.x, mA.x), fmaf(0.01f, nA.y, mA.y),
                                  fmaf(0.01f, nA.z, mA.z), fmaf(0.01f, nA.w, mA.w));
    outn[2 * p + 1] = make_float4(fmaf(0.01f, nB.x, mB.x), fmaf(0.01f, nB.y, mB.y),
                                  fmaf(0.01f, nB.z, mB.z), fmaf(0.01f, nB.w, mB.w));
}

extern "C" void kernel_launch(void* const* d_in, const int* in_sizes, int n_in,
                              void* d_out, int out_size, void* d_ws, size_t ws_size,
                              hipStream_t stream) {
    const float* params = (const float*)d_in[0];
    const float* design = (const float*)d_in[1];
    const float* noise  = (const float*)d_in[2];
    float* out = (float*)d_out;
    int B = in_sizes[0] / 3;
    int block = 256;
    // 2 lanes per system -> B*2 threads
    long long threads = (long long)B * 2;
    int grid = (int)((threads + block - 1) / block);
    stats5_kernel<<<grid, block, 0, stream>>>(params, design, noise, out, B);
}

// Round 9
// 87.483 us; speedup vs baseline: 1.1669x; 1.0068x over previous
//
#include <hip/hip_runtime.h>
#include <math.h>

#define NSTEP 69
#define OBS 8

namespace {

constexpr float kDT = 60.0f / 69.0f;

constexpr float interp_e(float t) {
    constexpr float DTm[16] = {0.f,2.f,4.f,6.f,8.f,10.f,12.f,14.f,16.f,18.f,20.f,25.f,30.f,40.f,50.f,60.f};
    constexpr float EP[16]  = {0.01713f,0.145f,0.2442f,0.7659f,1.0f,0.8605f,0.7829f,0.5705f,
                               0.6217f,0.331f,0.3388f,0.3116f,0.05062f,0.02504f,0.01163f,0.01163f};
    if (t >= 60.0f) return EP[15];
    if (t <= 0.0f)  return EP[0];
    int k = 0;
    for (int m = 0; m < 15; m++) if (t >= DTm[m]) k = m;
    float u = (t - DTm[k]) / (DTm[k + 1] - DTm[k]);
    return EP[k] + u * (EP[k + 1] - EP[k]);
}

// {lo, mid, hi, pad} per step, padded so the distance-1 prefetch stays in bounds.
struct EQuad { float lo, mid, hi, pad; };
struct ETab4 { EQuad q[NSTEP + 1]; };

constexpr ETab4 make_etab4() {
    ETab4 e{};
    for (int s = 0; s < NSTEP; s++) {
        float t0 = (float)s * kDT;
        e.q[s].lo  = interp_e(t0);
        e.q[s].mid = interp_e(t0 + 0.5f * kDT);
        e.q[s].hi  = interp_e(t0 + kDT);
        e.q[s].pad = 0.0f;
    }
    e.q[NSTEP] = e.q[NSTEP - 1];
    return e;
}

} // namespace

__constant__ ETab4 ETAB4 = make_etab4();

// Phase-pinned RK4.
//
// R0-R8 evidence: kernel is pinned at 37-52us under every code shape; VALU
// busy 31% at 1 wave/SIMD with ZERO loop memory ops (R0: pure literals).
// Surviving theories: (a) per-wave i-fetch cadence ~6.5 cyc/instr, or
// (b) the compiler emits a near-serial schedule every time (tell: it picks
// 44-64 VGPR despite 256-512 budgets; 6.5 cyc ~= fma forwarding latency).
// This version discriminates: the body is written phase-major (each phase =
// 11-22 mutually independent ops on named scalars) with
// __builtin_amdgcn_sched_barrier(0) pinning phase boundaries, so the
// scheduler cannot serialize chains to shrink live ranges. Arithmetic is
// operation-identical to the R3 scalar version.
#define SBAR __builtin_amdgcn_sched_barrier(0)

__global__ __launch_bounds__(256, 1) void stats5_kernel(
    const float* __restrict__ params,
    const float* __restrict__ design,
    const float* __restrict__ noise,
    float* __restrict__ out,
    int B)
{
    int b = blockIdx.x * blockDim.x + threadIdx.x;
    if (b >= B) return;

    // ---- design readout (wave-uniform -> SGPR)
    int ij[OBS], ij1[OBS]; float wj[OBS], w1j[OBS];
    #pragma unroll
    for (int j = 0; j < OBS; j++) {
        float pos = design[j] * (1.0f / kDT);
        int i = (int)pos;
        i = i < 0 ? 0 : (i > NSTEP - 1 ? NSTEP - 1 : i);
        float w = pos - (float)i;
        ij[j]  = __builtin_amdgcn_readfirstlane(i);
        ij1[j] = ij[j] + 1;
        int wb = __builtin_amdgcn_readfirstlane(__float_as_int(w));
        wj[j]  = __int_as_float(wb);
        w1j[j] = 1.0f - wj[j];
    }

    unsigned long long m_lo = 0ull, m_hi = 0ull;
    #pragma unroll
    for (int j = 0; j < OBS; j++) {
        if (ij[j]  < 64) m_lo |= 1ull << ij[j];  else m_hi |= 1ull << (ij[j]  - 64);
        if (ij1[j] < 64) m_lo |= 1ull << ij1[j]; else m_hi |= 1ull << (ij1[j] - 64);
    }

    // ---- parameter transform
    float p0 = params[3 * b], p1 = params[3 * b + 1], p2 = params[3 * b + 2];
    const float INV_SQRT2 = 0.7071067811865476f;
    float k1  = fmaf(0.5f * erfcf(-p0 * INV_SQRT2), 2.5f,  0.5f);
    float k2  = fmaf(0.5f * erfcf(-p1 * INV_SQRT2), 0.15f, 0.05f);
    float tau = fmaf(0.5f * erfcf(-p2 * INV_SQRT2), 6.0f,  4.0f);
    float r   = 8.0f / tau;

    const float hdt = 0.5f * kDT;
    const float c6  = kDT * (1.0f / 6.0f);
    const float k2r = 0.125f * k2 * tau;   // k2 / r (no division)
    const float crh = hdt * r;             // half-step chain scale
    const float crf = kDT * r;             // full-step chain scale
    const float c6r = c6 * r;              // final chain scale

    // ---- hoist epilogue loads
    long long base = (long long)b * 16;
    long long nb   = (long long)B * 16;
    const float4* nz = (const float4*)(noise + base);
    float4 n0 = nz[0], n1 = nz[1], n2 = nz[2], n3 = nz[3];

    float a12[OBS], a0[OBS], b12[OBS], b0[OBS];
    #pragma unroll
    for (int j = 0; j < OBS; j++) { a12[j] = 0.f; a0[j] = 0.f; b12[j] = 0.f; b0[j] = 0.f; }

    float x0 = 3.71f, x1 = 0.f, x2 = 0.f;
    float W0 = 0.f, W1 = 0.f, W2 = 0.f, W3 = 0.f;
    float W4 = 0.f, W5 = 0.f, W6 = 0.f, W7 = 0.f;

    if (m_lo & 1ull) {
        #pragma unroll
        for (int j = 0; j < OBS; j++)
            if (ij[j] == 0) { a12[j] = 0.f; a0[j] = 3.71f; }
    }

    const float4* et = reinterpret_cast<const float4*>(&ETAB4.q[0].lo);
    float4 eC = et[0];

    #pragma unroll 1
    for (int s = 0; s < NSTEP; s++) {
        float4 eN = et[s + 1];
        float k1a = k1 * eC.x, k1b = k1 * eC.y, k1c = k1 * eC.z;

        // ======== stage 1: derivs at (x, W) — 13 independent ops ========
        float a1  = k1a * x0;
        float q1s = x1 * x1;
        float d10 = fmaf(k2r, W7, -a1);
        float d11 = a1 - q1s;
        float d12 = fmaf(-k2, x2, q1s);
        float g10 = fmaf(r, x2, -W0);
        float g11 = W0 - W1, g12 = W1 - W2, g13 = W2 - W3, g14 = W3 - W4;
        float g15 = W4 - W5, g16 = W5 - W6, g17 = W6 - W7;
        SBAR;
        // ---- stage-1 updates — 11 independent fmas
        float t0 = fmaf(hdt, d10, x0), t1 = fmaf(hdt, d11, x1), t2 = fmaf(hdt, d12, x2);
        float u0 = fmaf(crh, g10, W0), u1 = fmaf(crh, g11, W1);
        float u2 = fmaf(crh, g12, W2), u3 = fmaf(crh, g13, W3);
        float u4 = fmaf(crh, g14, W4), u5 = fmaf(crh, g15, W5);
        float u6 = fmaf(crh, g16, W6), u7 = fmaf(crh, g17, W7);
        SBAR;
        // ======== stage 2: derivs at (t, u) ========
        float a2  = k1b * t0;
        float q2s = t1 * t1;
        float d20 = fmaf(k2r, u7, -a2);
        float d21 = a2 - q2s;
        float d22 = fmaf(-k2, t2, q2s);
        float g20 = fmaf(r, t2, -u0);
        float g21 = u0 - u1, g22 = u1 - u2, g23 = u2 - u3, g24 = u3 - u4;
        float g25 = u4 - u5, g26 = u5 - u6, g27 = u6 - u7;
        SBAR;
        // ---- stage-2 updates + accumulator init — 22 independent ops
        float ax0 = fmaf(2.0f, d20, d10), ax1 = fmaf(2.0f, d21, d11), ax2 = fmaf(2.0f, d22, d12);
        float A0 = fmaf(2.0f, g20, g10), A1 = fmaf(2.0f, g21, g11);
        float A2 = fmaf(2.0f, g22, g12), A3 = fmaf(2.0f, g23, g13);
        float A4 = fmaf(2.0f, g24, g14), A5 = fmaf(2.0f, g25, g15);
        float A6 = fmaf(2.0f, g26, g16), A7 = fmaf(2.0f, g27, g17);
        t0 = fmaf(hdt, d20, x0); t1 = fmaf(hdt, d21, x1); t2 = fmaf(hdt, d22, x2);
        u0 = fmaf(crh, g20, W0); u1 = fmaf(crh, g21, W1);
        u2 = fmaf(crh, g22, W2); u3 = fmaf(crh, g23, W3);
        u4 = fmaf(crh, g24, W4); u5 = fmaf(crh, g25, W5);
        u6 = fmaf(crh, g26, W6); u7 = fmaf(crh, g27, W7);
        SBAR;
        // ======== stage 3: derivs at (t, u) ========
        float a3  = k1b * t0;
        float q3s = t1 * t1;
        float d30 = fmaf(k2r, u7, -a3);
        float d31 = a3 - q3s;
        float d32 = fmaf(-k2, t2, q3s);
        float g30 = fmaf(r, t2, -u0);
        float g31 = u0 - u1, g32 = u1 - u2, g33 = u2 - u3, g34 = u3 - u4;
        float g35 = u4 - u5, g36 = u5 - u6, g37 = u6 - u7;
        SBAR;
        // ---- stage-3 updates + accumulate — 22 independent ops
        ax0 = fmaf(2.0f, d30, ax0); ax1 = fmaf(2.0f, d31, ax1); ax2 = fmaf(2.0f, d32, ax2);
        A0 = fmaf(2.0f, g30, A0); A1 = fmaf(2.0f, g31, A1);
        A2 = fmaf(2.0f, g32, A2); A3 = fmaf(2.0f, g33, A3);
        A4 = fmaf(2.0f, g34, A4); A5 = fmaf(2.0f, g35, A5);
        A6 = fmaf(2.0f, g36, A6); A7 = fmaf(2.0f, g37, A7);
        t0 = fmaf(kDT, d30, x0); t1 = fmaf(kDT, d31, x1); t2 = fmaf(kDT, d32, x2);
        u0 = fmaf(crf, g30, W0); u1 = fmaf(crf, g31, W1);
        u2 = fmaf(crf, g32, W2); u3 = fmaf(crf, g33, W3);
        u4 = fmaf(crf, g34, W4); u5 = fmaf(crf, g35, W5);
        u6 = fmaf(crf, g36, W6); u7 = fmaf(crf, g37, W7);
        SBAR;
        // ======== stage 4: derivs at (t, u) ========
        float a4  = k1c * t0;
        float q4s = t1 * t1;
        float d40 = fmaf(k2r, u7, -a4);
        float d41 = a4 - q4s;
        float d42 = fmaf(-k2, t2, q4s);
        float g40 = fmaf(r, t2, -u0);
        float g41 = u0 - u1, g42 = u1 - u2, g43 = u2 - u3, g44 = u3 - u4;
        float g45 = u4 - u5, g46 = u5 - u6, g47 = u6 - u7;
        SBAR;
        // ---- final combine — 11 adds then 11 independent fmas
        ax0 += d40; ax1 += d41; ax2 += d42;
        A0 += g40; A1 += g41; A2 += g42; A3 += g43;
        A4 += g44; A5 += g45; A6 += g46; A7 += g47;
        x0 = fmaf(c6, ax0, x0); x1 = fmaf(c6, ax1, x1); x2 = fmaf(c6, ax2, x2);
        W0 = fmaf(c6r, A0, W0); W1 = fmaf(c6r, A1, W1);
        W2 = fmaf(c6r, A2, W2); W3 = fmaf(c6r, A3, W3);
        W4 = fmaf(c6r, A4, W4); W5 = fmaf(c6r, A5, W5);
        W6 = fmaf(c6r, A6, W6); W7 = fmaf(c6r, A7, W7);
        SBAR;

        // uniform observation-mask test: SALU + s_cbranch, taken <=16/69
        const int ti = s + 1;
        unsigned long long mm = (ti < 64) ? (m_lo >> ti) : (m_hi >> (ti - 64));
        if (__builtin_expect((int)(mm & 1ull), 0)) {
            float s12 = x1 + x2;
            #pragma unroll
            for (int j = 0; j < OBS; j++) {
                if (ti == ij[j])  { a12[j] = s12; a0[j] = x0; }
                if (ti == ij1[j]) { b12[j] = s12; b0[j] = x0; }
            }
        }
        eC = eN;
    }

    float o1[OBS], o2[OBS];
    #pragma unroll
    for (int j = 0; j < OBS; j++) {
        o1[j] = 0.33f * fmaf(w1j[j], a12[j], wj[j] * b12[j]);
        o2[j] = 0.26f * fmaf(w1j[j], a0[j] + a12[j], wj[j] * (b0[j] + b12[j]));
    }

    float4* outv = (float4*)(out + base);
    float4* outn = (float4*)(out + nb + base);

    float4 v0 = make_float4(o1[0], o1[1], o1[2], o1[3]);
    float4 v1 = make_float4(o1[4], o1[5], o1[6], o1[7]);
    float4 v2 = make_float4(o2[0], o2[1], o2[2], o2[3]);
    float4 v3 = make_float4(o2[4], o2[5], o2[6], o2[7]);
    outv[0] = v0; outv[1] = v1; outv[2] = v2; outv[3] = v3;

    outn[0] = make_float4(fmaf(0.01f, n0.x, v0.x), fmaf(0.01f, n0.y, v0.y),
                          fmaf(0.01f, n0.z, v0.z), fmaf(0.01f, n0.w, v0.w));
    outn[1] = make_float4(fmaf(0.01f, n1.x, v1.x), fmaf(0.01f, n1.y, v1.y),
                          fmaf(0.01f, n1.z, v1.z), fmaf(0.01f, n1.w, v1.w));
    outn[2] = make_float4(fmaf(0.01f, n2.x, v2.x), fmaf(0.01f, n2.y, v2.y),
                          fmaf(0.01f, n2.z, v2.z), fmaf(0.01f, n2.w, v2.w));
    outn[3] = make_float4(fmaf(0.01f, n3.x, v3.x), fmaf(0.01f, n3.y, v3.y),
                          fmaf(0.01f, n3.z, v3.z), fmaf(0.01f, n3.w, v3.w));
}

extern "C" void kernel_launch(void* const* d_in, const int* in_sizes, int n_in,
                              void* d_out, int out_size, void* d_ws, size_t ws_size,
                              hipStream_t stream) {
    const float* params = (const float*)d_in[0];
    const float* design = (const float*)d_in[1];
    const float* noise  = (const float*)d_in[2];
    float* out = (float*)d_out;
    int B = in_sizes[0] / 3;
    int block = 256;
    int grid = (B + block - 1) / block;
    stats5_kernel<<<grid, block, 0, stream>>>(params, design, noise, out, B);
}